// Round 4
// baseline (463.520 us; speedup 1.0000x reference)
//
#include <hip/hip_runtime.h>
#include <hip/hip_bf16.h>
#include <stdint.h>

#define M_DIM 4096
#define K_DIM 4096
#define N_DIM 2048
#define B_DIM 4
#define NNZ_PER_ROW 409
#define NNZ_TOT (M_DIM * NNZ_PER_ROW)

typedef unsigned short u16;
typedef short short8 __attribute__((ext_vector_type(8)));
typedef float f32x16 __attribute__((ext_vector_type(16)));

__device__ __forceinline__ u16 f2bf(float f) {
    __hip_bfloat16 h = __float2bfloat16(f);
    u16 s;
    __builtin_memcpy(&s, &h, 2);
    return s;
}

// async global->LDS, 16 bytes per lane; LDS dest = wave-uniform base + lane*16
__device__ __forceinline__ void lds16(const u16* g, u16* l) {
    __builtin_amdgcn_global_load_lds(
        (__attribute__((address_space(1))) void*)g,
        (__attribute__((address_space(3))) void*)l,
        16, 0, 0);
}

// ---------------------------------------------------------------------------
// Kernel 1: x fp32 -> bf16. Each lane: 32 B read (2x float4), 16 B write.
// ---------------------------------------------------------------------------
__global__ void cvt_x(const float* __restrict__ in, u16* __restrict__ out) {
    int i = blockIdx.x * blockDim.x + threadIdx.x;  // 8 elements per thread
    float4 a = reinterpret_cast<const float4*>(in)[2 * i];
    float4 b = reinterpret_cast<const float4*>(in)[2 * i + 1];
    union { u16 u[8]; uint4 v; } o;
    o.u[0] = f2bf(a.x); o.u[1] = f2bf(a.y); o.u[2] = f2bf(a.z); o.u[3] = f2bf(a.w);
    o.u[4] = f2bf(b.x); o.u[5] = f2bf(b.y); o.u[6] = f2bf(b.z); o.u[7] = f2bf(b.w);
    reinterpret_cast<uint4*>(out)[i] = o.v;
}

// ---------------------------------------------------------------------------
// Kernel 2: CSR row -> dense bf16 W row, one block per row.
// ---------------------------------------------------------------------------
__global__ __launch_bounds__(256) void scatter_w(const float* __restrict__ vals,
                                                 const int* __restrict__ cols,
                                                 u16* __restrict__ W) {
    __shared__ float row[K_DIM];  // 16 KB
    const int t = threadIdx.x;
    const int m = blockIdx.x;
#pragma unroll
    for (int c = t; c < K_DIM; c += 256) row[c] = 0.0f;
    __syncthreads();
    const int base = m * NNZ_PER_ROW;
    for (int j = t; j < NNZ_PER_ROW; j += 256)
        atomicAdd(&row[cols[base + j]], vals[base + j]);
    __syncthreads();
    u16* Wr = W + (size_t)m * K_DIM + t * 16;
#pragma unroll
    for (int h = 0; h < 2; ++h) {
        union { u16 u[8]; uint4 v; } o;
#pragma unroll
        for (int e = 0; e < 8; ++e) o.u[e] = f2bf(row[t * 16 + h * 8 + e]);
        reinterpret_cast<uint4*>(Wr)[h] = o.v;
    }
}

// ---------------------------------------------------------------------------
// Kernel 3: NT GEMM, 256x256 tile, BK=64, 32x32x16 MFMA, 2-phase/K-tile
// single-barrier schedule (R4).
//   8 waves = 2(M) x 4(N); wave owns 128x64 C as 4x2 tiles of 32x32
//   (acc[4][2] f32x16 = 128 regs). Per K-tile (BK=64 = 4 ksteps of 16):
//     phase A: ds_read A-half0 (8 b128) + B0 (4) + B1 (4); stage A1(t+1);
//              lgkm(0); MFMA m-tiles{0,1} x n{0,1} x 4k = 16; barrier.
//     phase B: ds_read A-half1 (8); stage B1(t+1), A0(t+2), B0(t+2);
//              lgkm(0); MFMA m-tiles{2,3} (reuses b0f/b1f) = 16; VM4; barrier.
//   24 b128 reads/wave/tile (LDS minimum, each byte once). ONE barrier per
//   phase: each wave's lgkm(0) covers its own reads; the end barrier makes
//   (a) all reads complete before any next-phase STAGE overwrites (WAR), and
//   (b) the per-wave VM4 globally visible (RAW for staged data). No lockstep
//   pre-MFMA barrier => waves self-stagger, ds_read overlaps other waves'
//   MFMA. VM4 leaves exactly {A0(t+2),B0(t+2)} in flight, forces t+1 landed.
//   Fragment layouts (32x32x16 bf16): A/B operand lane l: row/col = l&31,
//   k = (l>>5)*8 + e. C/D: col = l&31, row = (r&3) + 8*(r>>2) + 4*(l>>5)
//   (m74/m101-verified). LDS chunk-XOR swizzle: chunk c of row r stored at
//   c ^ (r&7); read key = lane&7, chunk(s) = (2s + (lane>>5)) ^ key.
// ---------------------------------------------------------------------------
#define NOPV ((void)0)
#define VM4 asm volatile("s_waitcnt vmcnt(4)" ::: "memory")
#define VM0 asm volatile("s_waitcnt vmcnt(0)" ::: "memory")

#define STAGE_A(BUF, H, KT) do {                                                  \
    lds16(Ag + (size_t)((H) * 128 +  0) * K_DIM + (size_t)(KT) * 64,              \
          &sA[BUF][(H) * 128 +  0 + wave * 8][0]);                                \
    lds16(Ag + (size_t)((H) * 128 + 64) * K_DIM + (size_t)(KT) * 64,              \
          &sA[BUF][(H) * 128 + 64 + wave * 8][0]);                                \
} while (0)

#define STAGE_B(BUF, H, KT) do {                                                  \
    lds16(Bg + (size_t)((H) * 128 +  0) * K_DIM + (size_t)(KT) * 64,              \
          &sB[BUF][(H) * 128 +  0 + wave * 8][0]);                                \
    lds16(Bg + (size_t)((H) * 128 + 64) * K_DIM + (size_t)(KT) * 64,              \
          &sB[BUF][(H) * 128 + 64 + wave * 8][0]);                                \
} while (0)

// fragment loads (all indices compile-time after unroll)
#define DS_A(BUF, MH) do {                                                        \
    _Pragma("unroll")                                                             \
    for (int i_ = 0; i_ < 2; ++i_) {                                              \
        const u16* p_ = &sA[BUF][wm * 128 + ((MH) * 2 + i_) * 32 + fm32][0];      \
        _Pragma("unroll")                                                         \
        for (int s_ = 0; s_ < 4; ++s_)                                            \
            af[i_][s_] = *(const short8*)(p_ + cc[s_]);                           \
    }                                                                             \
} while (0)

#define DS_B(BUF, NT, ARR) do {                                                   \
    const u16* p_ = &sB[BUF][wn * 64 + (NT) * 32 + fm32][0];                      \
    _Pragma("unroll")                                                             \
    for (int s_ = 0; s_ < 4; ++s_)                                                \
        ARR[s_] = *(const short8*)(p_ + cc[s_]);                                  \
} while (0)

#define MFMA_HALF(MH) do {                                                        \
    _Pragma("unroll")                                                             \
    for (int i_ = 0; i_ < 2; ++i_) {                                              \
        _Pragma("unroll")                                                         \
        for (int s_ = 0; s_ < 4; ++s_) {                                          \
            acc[(MH) * 2 + i_][0] = __builtin_amdgcn_mfma_f32_32x32x16_bf16(      \
                af[i_][s_], b0f[s_], acc[(MH) * 2 + i_][0], 0, 0, 0);             \
            acc[(MH) * 2 + i_][1] = __builtin_amdgcn_mfma_f32_32x32x16_bf16(      \
                af[i_][s_], b1f[s_], acc[(MH) * 2 + i_][1], 0, 0, 0);             \
        }                                                                         \
    }                                                                             \
} while (0)

// phase A: reads A-half0 + both B halves; 16 MFMAs; one barrier
#define PHA(BUF, STAGE_STMT) do {                                                 \
    DS_A(BUF, 0);                                                                 \
    DS_B(BUF, 0, b0f);                                                            \
    DS_B(BUF, 1, b1f);                                                            \
    STAGE_STMT;                                                                   \
    asm volatile("s_waitcnt lgkmcnt(0)" ::: "memory");                            \
    __builtin_amdgcn_sched_barrier(0);                                            \
    __builtin_amdgcn_s_setprio(1);                                                \
    MFMA_HALF(0);                                                                 \
    __builtin_amdgcn_s_setprio(0);                                                \
    asm volatile("" ::: "memory");                                                \
    __builtin_amdgcn_s_barrier();                                                 \
} while (0)

// phase B: reads A-half1 (reuses b0f/b1f); 16 MFMAs; [vmcnt]; one barrier
#define PHB(BUF, STAGE_STMT, WAIT_STMT) do {                                      \
    DS_A(BUF, 1);                                                                 \
    STAGE_STMT;                                                                   \
    asm volatile("s_waitcnt lgkmcnt(0)" ::: "memory");                            \
    __builtin_amdgcn_sched_barrier(0);                                            \
    __builtin_amdgcn_s_setprio(1);                                                \
    MFMA_HALF(1);                                                                 \
    __builtin_amdgcn_s_setprio(0);                                                \
    WAIT_STMT;                                                                    \
    asm volatile("" ::: "memory");                                                \
    __builtin_amdgcn_s_barrier();                                                 \
} while (0)

__global__ __launch_bounds__(512, 2) void gemm_bt(
    const u16* __restrict__ A,
    const u16* __restrict__ Bt,
    float* __restrict__ C) {
    __shared__ __align__(16) u16 sA[2][256][64];  // 64 KB
    __shared__ __align__(16) u16 sB[2][256][64];  // 64 KB

    const int tid  = threadIdx.x;
    const int wave = tid >> 6;
    const int lane = tid & 63;
    const int wm = wave >> 2;     // 0..1 (M)
    const int wn = wave & 3;      // 0..3 (N)

    // XCD-aware bijective swizzle of the 128 (m,n) tiles per batch
    int wg  = blockIdx.y * 8 + blockIdx.x;          // 0..127
    int swz = (wg & 7) * 16 + (wg >> 3);
    const int bn0 = (swz & 7) * 256;
    const int bm0 = (swz >> 3) * 256;
    const int bat = blockIdx.z;

    // staging: lane covers row (lane>>3) of an 8-row group; global 16B chunk
    // is (lane&7) ^ (lane>>3)  [pre-swizzled source, linear LDS dest]
    const int slr = lane >> 3;
    const int slc = ((lane & 7) ^ slr) * 8;
    const u16* Ag = A + (size_t)(bm0 + wave * 8 + slr) * K_DIM + slc;
    const u16* Bg = Bt + (size_t)bat * N_DIM * K_DIM
                      + (size_t)(bn0 + wave * 8 + slr) * K_DIM + slc;

    // 32x32x16 fragment decomposition: row/col = lane&31, k-group = lane>>5
    const int fm32 = lane & 31;
    const int ka   = lane >> 5;          // 0..1
    const int key  = lane & 7;           // swizzle key = row & 7
    int cc[4];
#pragma unroll
    for (int s = 0; s < 4; ++s) cc[s] = ((2 * s + ka) ^ key) * 8;  // elems

    f32x16 acc[4][2] = {};   // [m-tile][n-tile], 128 regs
    short8 af[2][4];         // A fragments of current half [i][kstep] (32 VGPR)
    short8 b0f[4];           // B n-tile 0, live phase A -> phase B  (16 VGPR)
    short8 b1f[4];           // B n-tile 1, live phase A -> phase B  (16 VGPR)

    // prologue: t0 fully + t1 halves A0,B0 (12 loads/wave); VM4 -> t0 landed.
    STAGE_A(0, 0, 0); STAGE_B(0, 0, 0);
    STAGE_A(0, 1, 0); STAGE_B(0, 1, 0);
    STAGE_A(1, 0, 1); STAGE_B(1, 0, 1);
    VM4;
    __builtin_amdgcn_s_barrier();

#pragma unroll 1
    for (int t = 0; t <= 60; t += 2) {
        // tile t (buf0)
        PHA(0, STAGE_A(1, 1, t + 1));
        PHB(0, { STAGE_B(1, 1, t + 1); STAGE_A(0, 0, t + 2); STAGE_B(0, 0, t + 2); }, VM4);
        // tile t+1 (buf1)
        PHA(1, STAGE_A(0, 1, t + 2));
        PHB(1, { STAGE_B(0, 1, t + 2); STAGE_A(1, 0, t + 3); STAGE_B(1, 0, t + 3); }, VM4);
    }
    // peel t = 62 (buf0): finish staging t63, drain fully before its reads
    PHA(0, STAGE_A(1, 1, 63));
    PHB(0, STAGE_B(1, 1, 63), VM0);
    // peel t = 63 (buf1): no staging left
    PHA(1, NOPV);
    PHB(1, NOPV, NOPV);

    // epilogue: C/D 32x32 layout col = lane&31 (n),
    // row = (r&3) + 8*(r>>2) + 4*ka  (m74/m101-verified)
    float* Cb = C + (size_t)bat * M_DIM * N_DIM;
#pragma unroll
    for (int a = 0; a < 4; ++a) {
        const int mbase = bm0 + wm * 128 + a * 32 + 4 * ka;
#pragma unroll
        for (int b = 0; b < 2; ++b) {
            const int n = bn0 + wn * 64 + b * 32 + fm32;
#pragma unroll
            for (int r = 0; r < 16; ++r) {
                const int m = mbase + (r & 3) + 8 * (r >> 2);
                Cb[(size_t)m * N_DIM + n] = acc[a][b][r];
            }
        }
    }
}

extern "C" void kernel_launch(void* const* d_in, const int* in_sizes, int n_in,
                              void* d_out, int out_size, void* d_ws, size_t ws_size,
                              hipStream_t stream) {
    const float* x    = (const float*)d_in[0];
    const float* vals = (const float*)d_in[1];
    // d_in[2] = row_offsets (structure fixed: row i starts at i*409)
    const int*   cols = (const int*)d_in[3];
    float* out = (float*)d_out;

    // workspace: [ W bf16 : 32 MB ][ Xb bf16 : 64 MB ]
    u16* W  = (u16*)d_ws;
    u16* Xb = (u16*)d_ws + (size_t)M_DIM * K_DIM;

    int n8 = (B_DIM * N_DIM * K_DIM) / 8;  // 4,194,304 threads
    cvt_x<<<dim3(n8 / 256), dim3(256), 0, stream>>>(x, Xb);

    scatter_w<<<dim3(M_DIM), dim3(256), 0, stream>>>(vals, cols, W);

    dim3 grid(N_DIM / 256, M_DIM / 256, B_DIM);
    gemm_bt<<<grid, dim3(512), 0, stream>>>(W, Xb, out);
}